// Round 17
// baseline (124.813 us; speedup 1.0000x reference)
//
#include <hip/hip_runtime.h>

typedef float  f32x4 __attribute__((ext_vector_type(4)));
typedef short  s16x8 __attribute__((ext_vector_type(8)));
typedef short  s16x4 __attribute__((ext_vector_type(4)));

#define DEVI static __device__ __forceinline__

// K=16 bf16 MFMA availability (gfx950 ISA has v_mfma_f32_16x16x16_bf16;
// LLVM builtin is historically the _1k name). Fallback build keeps the
// K=32-layout tail tile (prep emits both layouts) => degrades to r16 exact.
#if defined(__has_builtin)
#  if __has_builtin(__builtin_amdgcn_mfma_f32_16x16x16_bf16_1k)
#    define MFMA16(a, b, c) __builtin_amdgcn_mfma_f32_16x16x16_bf16_1k(a, b, c, 0, 0, 0)
#    define HAVE_MFMA16 1
#  elif __has_builtin(__builtin_amdgcn_mfma_f32_16x16x16_bf16)
#    define MFMA16(a, b, c) __builtin_amdgcn_mfma_f32_16x16x16_bf16(a, b, c, 0, 0, 0)
#    define HAVE_MFMA16 1
#  endif
#endif
#ifndef HAVE_MFMA16
#  define HAVE_MFMA16 0
#endif

DEVI short f2b(float f) {
  unsigned u = __builtin_bit_cast(unsigned, f);
  unsigned r = (u + 0x7FFFu + ((u >> 16) & 1u)) >> 16;   // RNE fp32->bf16
  return (short)(unsigned short)r;
}
DEVI float b2f(short s) {
  unsigned u = ((unsigned)(unsigned short)s) << 16;
  return __builtin_bit_cast(float, u);
}
// packed fp32x2 -> bf16x2 (round-half-up) via v_perm_b32 builtin (no inline asm).
DEVI unsigned pk2(float lo, float hi) {
  unsigned a = __builtin_bit_cast(unsigned, lo) + 0x8000u;
  unsigned b = __builtin_bit_cast(unsigned, hi) + 0x8000u;
  return __builtin_amdgcn_perm(b, a, 0x07060302u);  // (bf16(hi)<<16)|bf16(lo)
}
DEVI s16x4 pack4(f32x4 v) {
  union { unsigned u[2]; s16x4 s; } t;
  t.u[0] = pk2(v[0], v[1]); t.u[1] = pk2(v[2], v[3]);
  return t.s;
}
DEVI s16x8 pack8(float4 a, float4 b) {
  union { unsigned u[4]; s16x8 s; } t;
  t.u[0] = pk2(a.x, a.y); t.u[1] = pk2(a.z, a.w);
  t.u[2] = pk2(b.x, b.y); t.u[3] = pk2(b.z, b.w);
  return t.s;
}

// async global(16B/lane) -> LDS DMA; lds dest must be wave-uniform base
DEVI void stage16(const short* g, short* l) {
  __builtin_amdgcn_global_load_lds(
      (const __attribute__((address_space(1))) unsigned int*)g,
      (__attribute__((address_space(3))) unsigned int*)l, 16, 0, 0);
}

// sine positional encoding, matches _sine_pos_encoding((8,8), 72) tiled x2 over n
DEVI float pos_val(int n, int c) {
  int i = (n & 63) >> 3, j = n & 7;
  float base; int cc;
  if (c < 72) { base = (float)(i + 1); cc = c; }
  else        { base = (float)(j + 1); cc = c - 72; }
  int m = cc >> 1;
  const float SC  = (float)(6.283185307179586 / 8.000001);   // 2*pi/(8+1e-6)
  const float LNT = (float)(9.210340371976184 / 36.0);       // ln(10000)/36
  float arg = base * SC * __expf(-(float)m * LNT);
  return (cc & 1) ? cosf(arg) : sinf(arg);
}

// qkv weight element for packed strip c (0-2: q|k 48 cols; 3-4: v), feature k
DEVI float wval(const float* __restrict__ W, int c, int l, int h, int k, float qsc) {
  float v = 0.f;
  if (c < 3) {
    int sc = c * 16 + (l & 15);
    if (sc < 24) v = W[(h * 24 + sc) * 144 + k] * qsc;
    else         v = W[(144 + h * 24 + (sc - 24)) * 144 + k];
  } else {
    int d = (c - 3) * 16 + (l & 15);
    if (d < 24) v = W[(288 + h * 24 + d) * 144 + k];
  }
  return v;
}

// ---------------- prologue: fragment-ordered weight/bias/pos precompute ----
// WF per (path,head), stride 28*512 shorts:
//   full tiles (c=0..4, ks=0..3) at (c*4+ks)*512: k = ks*32+(l>>4)*8+j (<128)
//   tail32 (c) at (20+c)*512 : k = 128+(l>>4)*8+j, zero for k>=144  [fallback]
//   tail16 (c) at 25*512 + c*256 : k = 128+(l>>4)*4+j (all valid)   [K16 path]
//   q strip (c<3, sc<24) pre-scaled by 24^-0.5 * log2(e).
// PF  : [path][h][ct 0..9); RPF : [h][w][mt] f32 *log2(e); POSB: [128][144] bf16
__global__ void prep_kernel(const float* __restrict__ w_self,
                            const float* __restrict__ w_mut,
                            const float* __restrict__ w_proj,
                            const float* __restrict__ rpb_table,
                            short* WF, short* PF, float* RPF, short* POSB)
{
  const float SCALE = 0.20412414523193154f;   // 24^-0.5
  const float LOG2E = 1.4426950408889634f;
  const float QSC   = SCALE * LOG2E;
  int b = blockIdx.x, l = threadIdx.x;
  if (b < 300) {
    int p = b / 150, r1 = b % 150, h = r1 / 25, r2 = r1 % 25, c = r2 / 5, ks = r2 % 5;
    const float* W = p ? w_mut : w_self;
    short* head = WF + (p * 6 + h) * 14336;
    if (ks < 4) {
      short* dst = head + (c * 4 + ks) * 512 + l * 8;
      #pragma unroll
      for (int j = 0; j < 8; ++j) {
        int k = ks * 32 + (l >> 4) * 8 + j;
        dst[j] = f2b(wval(W, c, l, h, k, QSC));
      }
    } else {
      short* d32 = head + (20 + c) * 512 + l * 8;
      #pragma unroll
      for (int j = 0; j < 8; ++j) {
        int k = 128 + (l >> 4) * 8 + j;
        d32[j] = f2b(k < 144 ? wval(W, c, l, h, k, QSC) : 0.f);
      }
      short* d16 = head + 25 * 512 + c * 256 + l * 4;
      #pragma unroll
      for (int j = 0; j < 4; ++j) {
        int k = 128 + (l >> 4) * 4 + j;
        d16[j] = f2b(wval(W, c, l, h, k, QSC));
      }
    }
  } else if (b < 408) {
    int b2 = b - 300, ct = b2 % 9, h = (b2 / 9) % 6, p = b2 / 54;
    int cf = ct * 16 + (l & 15);
    short* dst = PF + b2 * 512 + l * 8;
    #pragma unroll
    for (int j = 0; j < 8; ++j) {
      int d = (l >> 4) * 8 + j;
      float v = (d < 24) ? w_proj[cf * 288 + (p ? 0 : 144) + h * 24 + d] : 0.f;
      dst[j] = f2b(v);
    }
  } else if (b < 792) {
    int b3 = b - 408, mt = b3 % 8, w = (b3 / 8) % 8, h = b3 / 64;
    int n = w * 16 + (l & 15);
    int dn = n >> 6, hn = (n >> 3) & 7, wn = n & 7;
    f32x4 o;
    #pragma unroll
    for (int r = 0; r < 4; ++r) {
      int m = mt * 16 + ((l >> 4) << 2) + r;
      int dm = m >> 6, hm = (m >> 3) & 7, wm = m & 7;
      int idx = (dn - dm + 1) * 225 + (hn - hm + 7) * 15 + (wn - wm + 7);
      o[r] = rpb_table[idx * 6 + h] * LOG2E;
    }
    *reinterpret_cast<f32x4*>(RPF + b3 * 256 + l * 4) = o;
  } else {
    int e = (b - 792) * 64 + l;           // 0..18431
    int n = e / 144, c = e - n * 144;
    POSB[e] = f2b(pos_val(n, c));
  }
}

#if HAVE_MFMA16
typedef s16x4 xt_t;
#else
typedef s16x8 xt_t;
#endif

// ---------------- main fused kernel ----------------
// r16 structure (119.7 us) + (a) rpb as beta-MFMA C-operand, (b) K=16 tail
// MFMA for qkv k=128..143 (was a half-zero K=32 step): -60 full-MFMA-equiv
// per wave, -8% WB staging/LDS-reads. Ledger: r13 setprio null; r14 barrier-C
// removal WRONG (don't re-attempt); r7/r9/r10 reg-heavy schemes spill at the
// 64-VGPR/(512,4) regime; r11 (512,2) halves occupancy.
// LDS: WB[25*512] + PFB[2*9*512] + QKB[128*56] + VTb[32*152] + AL[8*16*40]
// = 78336 B -> 2 blocks/CU.
template<int PATH>
DEVI void run_path(short* WB, short* PFB, short* QKB, short* VTb, short* AL,
                   const short* WF, const short* PF, const float* RPF,
                   const s16x8 (&xf)[4], xt_t xt, f32x4 (&oacc)[9],
                   int w, int lg, int ll, int l64)
{
  constexpr int NKS = PATH ? 2 : 4;          // PV k-steps (32 m each)
  const int mbase = PATH ? (w >> 2) * 64 : 0;
  const int qrow0 = (PATH ? (w ^ 4) : w) * 16;
  const f32x4 z4 = {0.f, 0.f, 0.f, 0.f};
  short* ALw = AL + (w * 16) * 40;           // wave-private staging rows

  for (int h = 0; h < 6; ++h) {
    __syncthreads();   // A: staged WB/PFB landed (barrier drains vmcnt) + prev-head LDS reads done
    // ---- qkv GEMM: 5 packed col-tiles x (4 full K-steps + 1 K=16 tail)
    #pragma unroll
    for (int c = 0; c < 5; ++c) {
      f32x4 acc = z4;
      #pragma unroll
      for (int ks = 0; ks < 4; ++ks) {
        s16x8 wa = *reinterpret_cast<const s16x8*>(&WB[(c * 4 + ks) * 512 + l64 * 8]);
        if (c < 3) acc = __builtin_amdgcn_mfma_f32_16x16x32_bf16(wa, xf[ks], acc, 0, 0, 0);
        else       acc = __builtin_amdgcn_mfma_f32_16x16x32_bf16(xf[ks], wa, acc, 0, 0, 0);
      }
#if HAVE_MFMA16
      {
        s16x4 wa4 = *reinterpret_cast<const s16x4*>(&WB[20 * 512 + c * 256 + l64 * 4]);
        if (c < 3) acc = MFMA16(wa4, xt, acc);
        else       acc = MFMA16(xt, wa4, acc);
      }
#else
      {
        s16x8 wa = *reinterpret_cast<const s16x8*>(&WB[(20 + c) * 512 + l64 * 8]);
        if (c < 3) acc = __builtin_amdgcn_mfma_f32_16x16x32_bf16(wa, xt, acc, 0, 0, 0);
        else       acc = __builtin_amdgcn_mfma_f32_16x16x32_bf16(xt, wa, acc, 0, 0, 0);
      }
#endif
      s16x4 o = pack4(acc);
      if (c < 3)        // q|k^T: C[cfeat][n] -> QKB[n=16w+ll][c*16+4lg+r]
        *reinterpret_cast<s16x4*>(&QKB[(w * 16 + ll) * 56 + c * 16 + lg * 4]) = o;
      else              // v: C[n][d] -> VTb[d=(c-3)*16+ll][16w+4lg+r]
        *reinterpret_cast<s16x4*>(&VTb[((c - 3) * 16 + ll) * 152 + w * 16 + lg * 4]) = o;
    }
    __syncthreads();   // B: q/k/vT ready; WB reads done
    s16x8 qf = {0, 0, 0, 0, 0, 0, 0, 0};     // lg=3 quarter = d-pad zeros
    if (lg < 3) qf = *reinterpret_cast<const s16x8*>(&QKB[(qrow0 + ll) * 56 + lg * 8]);
    // ---- issue async staging of NEXT head's weights (overlaps attn+PV+proj)
    {
      const short* nwf = nullptr; const short* npf = nullptr;
      if (h < 5) {
        nwf = WF + (PATH * 6 + h + 1) * 14336;
        npf = PF + (PATH * 6 + h + 1) * 9 * 512;
      } else if (PATH == 0) {
        nwf = WF + 6 * 14336;
        npf = PF + 6 * 9 * 512;
      }
      if (nwf) {
        int nb = (h + 1) & 1;
        #pragma unroll
        for (int r = 0; r < 3; ++r) {
          int slot = r * 8 + w;
          if (slot < 20) stage16(nwf + slot * 512 + l64 * 8, WB + slot * 512);
        }
#if HAVE_MFMA16
        if (w < 3) stage16(nwf + (25 + w) * 512 + l64 * 8, WB + (20 + w) * 512);
#else
        if (w < 5) stage16(nwf + (20 + w) * 512 + l64 * 8, WB + (20 + w) * 512);
#endif
        #pragma unroll
        for (int r = 0; r < 2; ++r) {
          int slot = r * 8 + w;
          if (slot < 9) stage16(npf + slot * 512 + l64 * 8, PFB + nb * 4608 + slot * 512);
        }
      }
    }
    // ---- beta (rpb in C-op) + exp2 + PV (deferred normalization)
    float vsum = 0.f;
    f32x4 pacc[2] = {z4, z4};
    #pragma unroll
    for (int ks = 0; ks < NKS; ++ks) {
      #pragma unroll
      for (int b2 = 0; b2 < 2; ++b2) {
        int mt = ks * 2 + b2;
        s16x8 kf = *reinterpret_cast<const s16x8*>(&QKB[(mbase + mt * 16 + ll) * 56 + 24 + lg * 8]);
        f32x4 cc = z4;
        if (PATH == 0)
          cc = *reinterpret_cast<const f32x4*>(RPF + (((h * 8 + w) * 8) + mt) * 256 + l64 * 4);
        f32x4 bb = __builtin_amdgcn_mfma_f32_16x16x32_bf16(kf, qf, cc, 0, 0, 0);
        f32x4 vv;
        #pragma unroll
        for (int r = 0; r < 4; ++r) vv[r] = __builtin_amdgcn_exp2f(bb[r]);
        vsum += (vv[0] + vv[1]) + (vv[2] + vv[3]);
        *reinterpret_cast<s16x4*>(&ALw[ll * 40 + b2 * 16 + lg * 4]) = pack4(vv);
      }
      s16x8 af = *reinterpret_cast<const s16x8*>(&ALw[ll * 40 + lg * 8]);
      #pragma unroll
      for (int dt = 0; dt < 2; ++dt) {
        s16x8 vf = *reinterpret_cast<const s16x8*>(&VTb[(dt * 16 + ll) * 152 + mbase + ks * 32 + lg * 8]);
        pacc[dt] = __builtin_amdgcn_mfma_f32_16x16x32_bf16(vf, af, pacc[dt], 0, 0, 0);
      }
    }
    vsum += __shfl_xor(vsum, 16, 64);
    vsum += __shfl_xor(vsum, 32, 64);
    float inv = 1.0f / vsum;
    // ---- out_h^T = pacc*inv -> ALw[n][d], then rank-24 proj update from PFB[h&1]
    #pragma unroll
    for (int dt = 0; dt < 2; ++dt) {
      f32x4 sc;
      #pragma unroll
      for (int r = 0; r < 4; ++r) sc[r] = pacc[dt][r] * inv;
      *reinterpret_cast<s16x4*>(&ALw[ll * 40 + dt * 16 + lg * 4]) = pack4(sc);
    }
    {
      s16x8 of = *reinterpret_cast<const s16x8*>(&ALw[ll * 40 + lg * 8]);
      const short* pfb = PFB + (h & 1) * 4608;
      #pragma unroll
      for (int ct = 0; ct < 9; ++ct) {
        s16x8 pf = *reinterpret_cast<const s16x8*>(&pfb[ct * 512 + l64 * 8]);
        oacc[ct] = __builtin_amdgcn_mfma_f32_16x16x32_bf16(of, pf, oacc[ct], 0, 0, 0);
      }
    }
  }
}

__global__ __launch_bounds__(512, 4)
void wmsa_kernel(const float* __restrict__ x,
                 const short* __restrict__ WF,
                 const short* __restrict__ PF,
                 const float* __restrict__ RPF,
                 const short* __restrict__ POSB,
                 const float* __restrict__ b_proj,
                 float* __restrict__ out)
{
  __shared__ short WB[25 * 512];
  __shared__ short PFB[2 * 9 * 512];
  __shared__ short QKB[128 * 56];
  __shared__ short VTb[32 * 152];
  __shared__ short AL[8 * 16 * 40];

  const int tid = threadIdx.x;
  const int w   = tid >> 6;
  const int l64 = tid & 63;
  const int lg  = l64 >> 4;
  const int ll  = l64 & 15;
  const int blk = blockIdx.x;

  f32x4 oacc[9];
  const f32x4 z4 = {0.f, 0.f, 0.f, 0.f};
  #pragma unroll
  for (int i = 0; i < 9; ++i) oacc[i] = z4;

  // prologue staging: WF[path0,h0] -> WB, PF[path0,h0] -> PFB[0]
  #pragma unroll
  for (int r = 0; r < 3; ++r) {
    int slot = r * 8 + w;
    if (slot < 20) stage16(WF + slot * 512 + l64 * 8, WB + slot * 512);
  }
#if HAVE_MFMA16
  if (w < 3) stage16(WF + (25 + w) * 512 + l64 * 8, WB + (20 + w) * 512);
#else
  if (w < 5) stage16(WF + (20 + w) * 512 + l64 * 8, WB + (20 + w) * 512);
#endif
  #pragma unroll
  for (int r = 0; r < 2; ++r) {
    int slot = r * 8 + w;
    if (slot < 9) stage16(PF + slot * 512 + l64 * 8, PFB + slot * 512);
  }
  // permanent zero stripe QKB cols 48-55 (beta K-pad); never overwritten
  if (tid < 128) {
    s16x8 zz = {0, 0, 0, 0, 0, 0, 0, 0};
    *reinterpret_cast<s16x8*>(&QKB[tid * 56 + 48]) = zz;
  }

  // x rows -> registers: 4 full K-chunks (cols 0..127) + tail (128..143)
  const int row = w * 16 + ll;
  const float* xr = x + (size_t)blk * (128 * 144) + row * 144;
  s16x8 xf[4];
  #pragma unroll
  for (int ks = 0; ks < 4; ++ks) {
    float4 a = *reinterpret_cast<const float4*>(xr + ks * 32 + lg * 8);
    float4 b = *reinterpret_cast<const float4*>(xr + ks * 32 + lg * 8 + 4);
    xf[ks] = pack8(a, b);
  }
  xt_t xt;
#if HAVE_MFMA16
  {
    float4 a = *reinterpret_cast<const float4*>(xr + 128 + lg * 4);
    f32x4 t = {a.x, a.y, a.z, a.w};
    xt = pack4(t);
  }
#else
  {
    s16x8 v = {0, 0, 0, 0, 0, 0, 0, 0};
    if (lg < 2) {
      float4 a = *reinterpret_cast<const float4*>(xr + 128 + lg * 8);
      float4 b = *reinterpret_cast<const float4*>(xr + 128 + lg * 8 + 4);
      v = pack8(a, b);
    }
    xt = v;
  }
#endif

  run_path<0>(WB, PFB, QKB, VTb, AL, WF, PF, RPF, xf, xt, oacc, w, lg, ll, l64);

  // xf/xt += pos (registers only; path-1 weights already staged at path-0 h=5)
  {
    const short* pb = POSB + row * 144;
    #pragma unroll
    for (int ks = 0; ks < 4; ++ks) {
      s16x8 pv = *reinterpret_cast<const s16x8*>(pb + ks * 32 + lg * 8);
      union { unsigned u[4]; s16x8 s; } t;
      #pragma unroll
      for (int j2 = 0; j2 < 4; ++j2) {
        float lo = b2f(xf[ks][2 * j2])     + b2f(pv[2 * j2]);
        float hi = b2f(xf[ks][2 * j2 + 1]) + b2f(pv[2 * j2 + 1]);
        t.u[j2] = pk2(lo, hi);
      }
      xf[ks] = t.s;
    }
#if HAVE_MFMA16
    {
      s16x4 pv = *reinterpret_cast<const s16x4*>(pb + 128 + lg * 4);
      union { unsigned u[2]; s16x4 s; } t;
      t.u[0] = pk2(b2f(xt[0]) + b2f(pv[0]), b2f(xt[1]) + b2f(pv[1]));
      t.u[1] = pk2(b2f(xt[2]) + b2f(pv[2]), b2f(xt[3]) + b2f(pv[3]));
      xt = t.s;
    }
#else
    if (lg < 2) {
      s16x8 pv = *reinterpret_cast<const s16x8*>(pb + 128 + lg * 8);
      union { unsigned u[4]; s16x8 s; } t;
      #pragma unroll
      for (int j2 = 0; j2 < 4; ++j2) {
        float lo = b2f(xt[2 * j2])     + b2f(pv[2 * j2]);
        float hi = b2f(xt[2 * j2 + 1]) + b2f(pv[2 * j2 + 1]);
        t.u[j2] = pk2(lo, hi);
      }
      xt = t.s;
    }
#endif
  }

  run_path<1>(WB, PFB, QKB, VTb, AL, WF, PF, RPF, xf, xt, oacc, w, lg, ll, l64);

  float* og = out + (size_t)blk * (128 * 144);
  #pragma unroll
  for (int ct = 0; ct < 9; ++ct) {
    int c = ct * 16 + ll;
    float bb = b_proj[c];
    #pragma unroll
    for (int r = 0; r < 4; ++r) {
      int n = w * 16 + lg * 4 + r;
      og[n * 144 + c] = oacc[ct][r] + bb;
    }
  }
}

extern "C" void kernel_launch(void* const* d_in, const int* in_sizes, int n_in,
                              void* d_out, int out_size, void* d_ws, size_t ws_size,
                              hipStream_t stream) {
  (void)in_sizes; (void)n_in; (void)out_size; (void)ws_size;
  const float* x   = (const float*)d_in[0];
  const float* rpb = (const float*)d_in[1];
  const float* wqs = (const float*)d_in[2];
  const float* wqm = (const float*)d_in[3];
  const float* wp  = (const float*)d_in[4];
  const float* bp  = (const float*)d_in[5];

  short* WF   = (short*)d_ws;                      // 12*14336 bf16 = 344064 B
  short* PF   = WF + 12 * 14336;                   // 108*512 bf16  = 110592 B
  float* RPF  = (float*)((char*)d_ws + 454656);    // 384*256 f32   = 393216 B
  short* POSB = (short*)((char*)d_ws + 847872);    // 18432 bf16    =  36864 B

  prep_kernel<<<dim3(1080), dim3(64), 0, stream>>>(wqs, wqm, wp, rpb, WF, PF, RPF, POSB);
  wmsa_kernel<<<dim3(1024), dim3(512), 0, stream>>>(x, WF, PF, RPF, POSB, bp, (float*)d_out);
}

// Round 18
// 117.101 us; speedup vs baseline: 1.0659x; 1.0659x over previous
//
#include <hip/hip_runtime.h>

typedef float  f32x4 __attribute__((ext_vector_type(4)));
typedef short  s16x8 __attribute__((ext_vector_type(8)));
typedef short  s16x4 __attribute__((ext_vector_type(4)));

#define DEVI static __device__ __forceinline__

DEVI short f2b(float f) {
  unsigned u = __builtin_bit_cast(unsigned, f);
  unsigned r = (u + 0x7FFFu + ((u >> 16) & 1u)) >> 16;   // RNE fp32->bf16
  return (short)(unsigned short)r;
}
DEVI float b2f(short s) {
  unsigned u = ((unsigned)(unsigned short)s) << 16;
  return __builtin_bit_cast(float, u);
}
// packed fp32x2 -> bf16x2 (round-half-up) via v_perm_b32 builtin (no inline asm).
DEVI unsigned pk2(float lo, float hi) {
  unsigned a = __builtin_bit_cast(unsigned, lo) + 0x8000u;
  unsigned b = __builtin_bit_cast(unsigned, hi) + 0x8000u;
  return __builtin_amdgcn_perm(b, a, 0x07060302u);  // (bf16(hi)<<16)|bf16(lo)
}
DEVI s16x4 pack4(f32x4 v) {
  union { unsigned u[2]; s16x4 s; } t;
  t.u[0] = pk2(v[0], v[1]); t.u[1] = pk2(v[2], v[3]);
  return t.s;
}
DEVI s16x8 pack8(float4 a, float4 b) {
  union { unsigned u[4]; s16x8 s; } t;
  t.u[0] = pk2(a.x, a.y); t.u[1] = pk2(a.z, a.w);
  t.u[2] = pk2(b.x, b.y); t.u[3] = pk2(b.z, b.w);
  return t.s;
}

// async global(16B/lane) -> LDS DMA; lds dest must be wave-uniform base
DEVI void stage16(const short* g, short* l) {
  __builtin_amdgcn_global_load_lds(
      (const __attribute__((address_space(1))) unsigned int*)g,
      (__attribute__((address_space(3))) unsigned int*)l, 16, 0, 0);
}

// sine positional encoding, matches _sine_pos_encoding((8,8), 72) tiled x2 over n
DEVI float pos_val(int n, int c) {
  int i = (n & 63) >> 3, j = n & 7;
  float base; int cc;
  if (c < 72) { base = (float)(i + 1); cc = c; }
  else        { base = (float)(j + 1); cc = c - 72; }
  int m = cc >> 1;
  const float SC  = (float)(6.283185307179586 / 8.000001);   // 2*pi/(8+1e-6)
  const float LNT = (float)(9.210340371976184 / 36.0);       // ln(10000)/36
  float arg = base * SC * __expf(-(float)m * LNT);
  return (cc & 1) ? cosf(arg) : sinf(arg);
}

// ---------------- prologue: fragment-ordered weight/bias/pos precompute ----
// WF : [path][h][combo c][ks] tiles of [64 lanes][8 bf16], 25 tiles/head:
//   c=0..2: PACKED q|k strip (48 cols, no d-padding): strip-col sc=c*16+(l&15);
//           sc<24 -> q row h*24+sc, scaled by 24^-0.5*log2(e);
//           sc>=24 -> k row 144+h*24+(sc-24), unscaled.
//   c=3,4 : v tile, d=(c-3)*16+(l&15), row 288+h*24+d, d<24 guard (zero pad).
//   lane l elem j covers K k=ks*32+(l>>4)*8+j, zero for k>=144.
// PF  : [path][h][ct 0..8]; lane l elem j = Wp[ct*16+(l&15)][COFF+h*24+(l>>4)*8+j]
// RPF : [h][w][mt] tiles of [64][4] f32, pre-scaled by log2(e)
// POSB: [128][144] bf16
__global__ void prep_kernel(const float* __restrict__ w_self,
                            const float* __restrict__ w_mut,
                            const float* __restrict__ w_proj,
                            const float* __restrict__ rpb_table,
                            short* WF, short* PF, float* RPF, short* POSB)
{
  const float SCALE = 0.20412414523193154f;   // 24^-0.5
  const float LOG2E = 1.4426950408889634f;
  int b = blockIdx.x, l = threadIdx.x;
  if (b < 300) {
    int p = b / 150, r1 = b % 150, h = r1 / 25, r2 = r1 % 25, c = r2 / 5, ks = r2 % 5;
    const float* W = p ? w_mut : w_self;
    short* dst = WF + b * 512 + l * 8;
    #pragma unroll
    for (int j = 0; j < 8; ++j) {
      int k = ks * 32 + (l >> 4) * 8 + j;
      float v = 0.f;
      if (k < 144) {
        if (c < 3) {
          int sc = c * 16 + (l & 15);
          if (sc < 24) v = W[(h * 24 + sc) * 144 + k] * (SCALE * LOG2E);
          else         v = W[(144 + h * 24 + (sc - 24)) * 144 + k];
        } else {
          int d = (c - 3) * 16 + (l & 15);
          if (d < 24) v = W[(288 + h * 24 + d) * 144 + k];
        }
      }
      dst[j] = f2b(v);
    }
  } else if (b < 408) {
    int b2 = b - 300, ct = b2 % 9, h = (b2 / 9) % 6, p = b2 / 54;
    int cf = ct * 16 + (l & 15);
    short* dst = PF + b2 * 512 + l * 8;
    #pragma unroll
    for (int j = 0; j < 8; ++j) {
      int d = (l >> 4) * 8 + j;
      float v = (d < 24) ? w_proj[cf * 288 + (p ? 0 : 144) + h * 24 + d] : 0.f;
      dst[j] = f2b(v);
    }
  } else if (b < 792) {
    int b3 = b - 408, mt = b3 % 8, w = (b3 / 8) % 8, h = b3 / 64;
    int n = w * 16 + (l & 15);
    int dn = n >> 6, hn = (n >> 3) & 7, wn = n & 7;
    f32x4 o;
    #pragma unroll
    for (int r = 0; r < 4; ++r) {
      int m = mt * 16 + ((l >> 4) << 2) + r;
      int dm = m >> 6, hm = (m >> 3) & 7, wm = m & 7;
      int idx = (dn - dm + 1) * 225 + (hn - hm + 7) * 15 + (wn - wm + 7);
      o[r] = rpb_table[idx * 6 + h] * LOG2E;
    }
    *reinterpret_cast<f32x4*>(RPF + b3 * 256 + l * 4) = o;
  } else {
    int e = (b - 792) * 64 + l;           // 0..18431
    int n = e / 144, c = e - n * 144;
    POSB[e] = f2b(pos_val(n, c));
  }
}

// ---------------- main fused kernel ----------------
// r16 structure EXACTLY (best measured: 119.7 us) + rpb as beta-MFMA C-operand
// (the proven component of r17: VALUBusy 36.7->34.9; the K=16-tail half was a
// complexity-for-nothing wash and is dropped). Ledger: r13 setprio null;
// r14 barrier-C-by-aliasing WRONG (r16's AL split removes it safely);
// r7/r9/r10 reg-heavy schemes spill at the 64-VGPR/(512,4) regime;
// r11 (512,2) halves occupancy; r17 K16-tail within noise.
// LDS: WB[25*512] + PFB[2*9*512] + QKB[128*56] + VTb[32*152] + AL[8*16*40]
// = 78336 B -> 2 blocks/CU.
template<int PATH>
DEVI void run_path(short* WB, short* PFB, short* QKB, short* VTb, short* AL,
                   const short* WF, const short* PF, const float* RPF,
                   const s16x8 (&xf)[5], f32x4 (&oacc)[9],
                   int w, int lg, int ll, int l64)
{
  constexpr int NKS = PATH ? 2 : 4;          // PV k-steps (32 m each)
  const int mbase = PATH ? (w >> 2) * 64 : 0;
  const int qrow0 = (PATH ? (w ^ 4) : w) * 16;
  const f32x4 z4 = {0.f, 0.f, 0.f, 0.f};
  short* ALw = AL + (w * 16) * 40;           // wave-private staging rows

  for (int h = 0; h < 6; ++h) {
    __syncthreads();   // A: staged WB/PFB landed (barrier drains vmcnt) + prev-head LDS reads done
    // ---- qkv GEMM from WB (LDS): wave's 16-row tile x 5 col-tiles (qk packed)
    #pragma unroll
    for (int c = 0; c < 5; ++c) {
      f32x4 acc = z4;
      #pragma unroll
      for (int ks = 0; ks < 5; ++ks) {
        s16x8 wa = *reinterpret_cast<const s16x8*>(&WB[(c * 5 + ks) * 512 + l64 * 8]);
        if (c < 3) acc = __builtin_amdgcn_mfma_f32_16x16x32_bf16(wa, xf[ks], acc, 0, 0, 0);
        else       acc = __builtin_amdgcn_mfma_f32_16x16x32_bf16(xf[ks], wa, acc, 0, 0, 0);
      }
      s16x4 o = pack4(acc);
      if (c < 3)        // q|k^T: C[cfeat][n] -> QKB[n=16w+ll][c*16+4lg+r]
        *reinterpret_cast<s16x4*>(&QKB[(w * 16 + ll) * 56 + c * 16 + lg * 4]) = o;
      else              // v: C[n][d] -> VTb[d=(c-3)*16+ll][16w+4lg+r]
        *reinterpret_cast<s16x4*>(&VTb[((c - 3) * 16 + ll) * 152 + w * 16 + lg * 4]) = o;
    }
    __syncthreads();   // B: q/k/vT ready; WB reads done
    s16x8 qf = {0, 0, 0, 0, 0, 0, 0, 0};     // lg=3 quarter = d-pad zeros
    if (lg < 3) qf = *reinterpret_cast<const s16x8*>(&QKB[(qrow0 + ll) * 56 + lg * 8]);
    // ---- issue async staging of NEXT head's weights (overlaps attn+PV+proj)
    {
      const short* nwf = nullptr; const short* npf = nullptr;
      if (h < 5) {
        nwf = WF + (PATH * 6 + h + 1) * 25 * 512;
        npf = PF + (PATH * 6 + h + 1) * 9 * 512;
      } else if (PATH == 0) {
        nwf = WF + 6 * 25 * 512;
        npf = PF + 6 * 9 * 512;
      }
      if (nwf) {
        int nb = (h + 1) & 1;
        #pragma unroll
        for (int r = 0; r < 4; ++r) {
          int slot = r * 8 + w;
          if (slot < 25) stage16(nwf + slot * 512 + l64 * 8, WB + slot * 512);
        }
        #pragma unroll
        for (int r = 0; r < 2; ++r) {
          int slot = r * 8 + w;
          if (slot < 9) stage16(npf + slot * 512 + l64 * 8, PFB + nb * 4608 + slot * 512);
        }
      }
    }
    // ---- beta (rpb in C-op) + exp2 + PV (deferred normalization;
    //      SCALE*log2e folded into q weights, rpb pre-scaled by log2e;
    //      kf cols 24..55 — 48-55 are permanent zeros)
    float vsum = 0.f;
    f32x4 pacc[2] = {z4, z4};
    #pragma unroll
    for (int ks = 0; ks < NKS; ++ks) {
      #pragma unroll
      for (int b2 = 0; b2 < 2; ++b2) {
        int mt = ks * 2 + b2;
        s16x8 kf = *reinterpret_cast<const s16x8*>(&QKB[(mbase + mt * 16 + ll) * 56 + 24 + lg * 8]);
        f32x4 cc = z4;
        if (PATH == 0)
          cc = *reinterpret_cast<const f32x4*>(RPF + (((h * 8 + w) * 8) + mt) * 256 + l64 * 4);
        f32x4 bb = __builtin_amdgcn_mfma_f32_16x16x32_bf16(kf, qf, cc, 0, 0, 0);
        f32x4 vv;
        #pragma unroll
        for (int r = 0; r < 4; ++r) vv[r] = __builtin_amdgcn_exp2f(bb[r]);
        vsum += (vv[0] + vv[1]) + (vv[2] + vv[3]);
        *reinterpret_cast<s16x4*>(&ALw[ll * 40 + b2 * 16 + lg * 4]) = pack4(vv);
      }
      s16x8 af = *reinterpret_cast<const s16x8*>(&ALw[ll * 40 + lg * 8]);
      #pragma unroll
      for (int dt = 0; dt < 2; ++dt) {
        s16x8 vf = *reinterpret_cast<const s16x8*>(&VTb[(dt * 16 + ll) * 152 + mbase + ks * 32 + lg * 8]);
        pacc[dt] = __builtin_amdgcn_mfma_f32_16x16x32_bf16(vf, af, pacc[dt], 0, 0, 0);
      }
    }
    vsum += __shfl_xor(vsum, 16, 64);
    vsum += __shfl_xor(vsum, 32, 64);
    float inv = 1.0f / vsum;
    // ---- out_h^T = pacc*inv -> ALw[n][d], then rank-24 proj update from PFB[h&1]
    #pragma unroll
    for (int dt = 0; dt < 2; ++dt) {
      f32x4 sc;
      #pragma unroll
      for (int r = 0; r < 4; ++r) sc[r] = pacc[dt][r] * inv;
      *reinterpret_cast<s16x4*>(&ALw[ll * 40 + dt * 16 + lg * 4]) = pack4(sc);
    }
    {
      s16x8 of = *reinterpret_cast<const s16x8*>(&ALw[ll * 40 + lg * 8]);
      const short* pfb = PFB + (h & 1) * 4608;
      #pragma unroll
      for (int ct = 0; ct < 9; ++ct) {
        s16x8 pf = *reinterpret_cast<const s16x8*>(&pfb[ct * 512 + l64 * 8]);
        oacc[ct] = __builtin_amdgcn_mfma_f32_16x16x32_bf16(of, pf, oacc[ct], 0, 0, 0);
      }
    }
  }
}

__global__ __launch_bounds__(512, 4)
void wmsa_kernel(const float* __restrict__ x,
                 const short* __restrict__ WF,
                 const short* __restrict__ PF,
                 const float* __restrict__ RPF,
                 const short* __restrict__ POSB,
                 const float* __restrict__ b_proj,
                 float* __restrict__ out)
{
  __shared__ short WB[25 * 512];
  __shared__ short PFB[2 * 9 * 512];
  __shared__ short QKB[128 * 56];
  __shared__ short VTb[32 * 152];
  __shared__ short AL[8 * 16 * 40];

  const int tid = threadIdx.x;
  const int w   = tid >> 6;
  const int l64 = tid & 63;
  const int lg  = l64 >> 4;
  const int ll  = l64 & 15;
  const int blk = blockIdx.x;

  f32x4 oacc[9];
  const f32x4 z4 = {0.f, 0.f, 0.f, 0.f};
  #pragma unroll
  for (int i = 0; i < 9; ++i) oacc[i] = z4;

  // prologue staging: WF[path0,h0] -> WB, PF[path0,h0] -> PFB[0]
  #pragma unroll
  for (int r = 0; r < 4; ++r) {
    int slot = r * 8 + w;
    if (slot < 25) stage16(WF + slot * 512 + l64 * 8, WB + slot * 512);
  }
  #pragma unroll
  for (int r = 0; r < 2; ++r) {
    int slot = r * 8 + w;
    if (slot < 9) stage16(PF + slot * 512 + l64 * 8, PFB + slot * 512);
  }
  // permanent zero stripe QKB cols 48-55 (beta K-pad); never overwritten
  if (tid < 128) {
    s16x8 zz = {0, 0, 0, 0, 0, 0, 0, 0};
    *reinterpret_cast<s16x8*>(&QKB[tid * 56 + 48]) = zz;
  }

  // x rows -> registers (K padded to 160 with zeros)
  s16x8 xf[5];
  const float* xr = x + (size_t)blk * (128 * 144) + (w * 16 + ll) * 144 + lg * 8;
  #pragma unroll
  for (int ks = 0; ks < 5; ++ks) {
    s16x8 v = {0, 0, 0, 0, 0, 0, 0, 0};
    if (ks < 4 || lg < 2) {
      float4 a = *reinterpret_cast<const float4*>(xr + ks * 32);
      float4 b = *reinterpret_cast<const float4*>(xr + ks * 32 + 4);
      v = pack8(a, b);
    }
    xf[ks] = v;
  }

  run_path<0>(WB, PFB, QKB, VTb, AL, WF, PF, RPF, xf, oacc, w, lg, ll, l64);

  // xf += pos (registers only; path-1 weights already staged during path-0 h=5)
  {
    const short* pr = POSB + (w * 16 + ll) * 144 + lg * 8;
    #pragma unroll
    for (int ks = 0; ks < 5; ++ks) {
      if (ks < 4 || lg < 2) {
        s16x8 pv = *reinterpret_cast<const s16x8*>(pr + ks * 32);
        union { unsigned u[4]; s16x8 s; } t;
        #pragma unroll
        for (int j2 = 0; j2 < 4; ++j2) {
          float lo = b2f(xf[ks][2 * j2])     + b2f(pv[2 * j2]);
          float hi = b2f(xf[ks][2 * j2 + 1]) + b2f(pv[2 * j2 + 1]);
          t.u[j2] = pk2(lo, hi);
        }
        xf[ks] = t.s;
      }
    }
  }

  run_path<1>(WB, PFB, QKB, VTb, AL, WF, PF, RPF, xf, oacc, w, lg, ll, l64);

  float* og = out + (size_t)blk * (128 * 144);
  #pragma unroll
  for (int ct = 0; ct < 9; ++ct) {
    int c = ct * 16 + ll;
    float bb = b_proj[c];
    #pragma unroll
    for (int r = 0; r < 4; ++r) {
      int n = w * 16 + lg * 4 + r;
      og[n * 144 + c] = oacc[ct][r] + bb;
    }
  }
}

extern "C" void kernel_launch(void* const* d_in, const int* in_sizes, int n_in,
                              void* d_out, int out_size, void* d_ws, size_t ws_size,
                              hipStream_t stream) {
  (void)in_sizes; (void)n_in; (void)out_size; (void)ws_size;
  const float* x   = (const float*)d_in[0];
  const float* rpb = (const float*)d_in[1];
  const float* wqs = (const float*)d_in[2];
  const float* wqm = (const float*)d_in[3];
  const float* wp  = (const float*)d_in[4];
  const float* bp  = (const float*)d_in[5];

  short* WF   = (short*)d_ws;                      // 300*512 bf16 = 307200 B
  short* PF   = WF + 300 * 512;                    // 108*512 bf16 = 110592 B
  float* RPF  = (float*)((char*)d_ws + 417792);    // 384*256 f32  = 393216 B
  short* POSB = (short*)((char*)d_ws + 811008);    // 18432 bf16   =  36864 B

  prep_kernel<<<dim3(1080), dim3(64), 0, stream>>>(wqs, wqm, wp, rpb, WF, PF, RPF, POSB);
  wmsa_kernel<<<dim3(1024), dim3(512), 0, stream>>>(x, WF, PF, RPF, POSB, bp, (float*)d_out);
}